// Round 6
// baseline (5731.794 us; speedup 1.0000x reference)
//
#include <hip/hip_runtime.h>
#include <math.h>
#include <limits.h>

#define BATCH 8
#define BEAM 4
#define VOCAB 32000
#define DMODEL 1024
#define MAXSEQ 32
#define PAD_ID 0
#define BOS_ID 1
#define EOS_ID 2
#define NROWS 32        // BATCH*BEAM
#define NBLK 500        // VOCAB/64 partial blocks
#define NPART 512       // padded partial stride

// ---------------- workspace layout (bytes) ----------------
// hT  [DMODEL][NROWS]   f32    @ 0        (131072)
// PMS [NROWS][NPART][2] f32    @ 131072   (131072)
// PV  [NROWS][NPART][4] f32    @ 262144   (262144)
// PI  [NROWS][NPART][4] i32    @ 524288   (262144)
// state @ 786432 (seqs/scores/finished/lengths/last_tok)
#define HT_OFF     0
#define PMS_OFF    131072
#define PV_OFF     262144
#define PI_OFF     524288
#define STATE_OFF  786432

__device__ __forceinline__ bool better(float av, int ai, float bv, int bi) {
  return (av > bv) || ((av == bv) && (ai < bi));
}

// sorted-descending insert, compile-time N
template<int N>
__device__ __forceinline__ void insN(float v, int i, float tv[N], int ti[N]) {
  if (better(v, i, tv[N-1], ti[N-1])) {
    tv[N-1] = v; ti[N-1] = i;
    #pragma unroll
    for (int j = N-1; j > 0; j--) {
      if (better(tv[j], ti[j], tv[j-1], ti[j-1])) {
        float fv = tv[j]; tv[j] = tv[j-1]; tv[j-1] = fv;
        int ii = ti[j]; ti[j] = ti[j-1]; ti[j-1] = ii;
      }
    }
  }
}

// per-row epilogue: wave-wide {max, sumexp, top4} for value v at column c
__device__ __forceinline__ void row_partials(
    float v, int c, int row, int p, int lane,
    float2* __restrict__ PMS, float4* __restrict__ PV, int4* __restrict__ PI) {
  float m = v;
  #pragma unroll
  for (int off = 32; off >= 1; off >>= 1) m = fmaxf(m, __shfl_xor(m, off));
  float s = expf(v - m);
  #pragma unroll
  for (int off = 32; off >= 1; off >>= 1) s += __shfl_xor(s, off);
  float myv = v; int myc = c; bool alive = true;
  float t4v[4]; int t4i[4];
  #pragma unroll
  for (int q = 0; q < 4; ++q) {
    float cv = alive ? myv : -INFINITY;
    int   ci = alive ? myc : INT_MAX;
    #pragma unroll
    for (int off = 32; off >= 1; off >>= 1) {
      float ov = __shfl_xor(cv, off);
      int   oi = __shfl_xor(ci, off);
      if (better(ov, oi, cv, ci)) { cv = ov; ci = oi; }
    }
    t4v[q] = cv; t4i[q] = ci;
    alive = alive && (ci != myc);
  }
  if (lane == 0) {
    PMS[row * NPART + p] = make_float2(m, s);
    PV[row * NPART + p]  = make_float4(t4v[0], t4v[1], t4v[2], t4v[3]);
    PI[row * NPART + p]  = make_int4(t4i[0], t4i[1], t4i[2], t4i[3]);
  }
}

// ---- kernel A: hT[c*32+r] = tanh(emb[tok_r] . Wdec[:,c] + b[c]) ----
template<bool INIT>
__global__ __launch_bounds__(256) void k_embdec(
    const float* __restrict__ emb, const float* __restrict__ Wdec,
    const float* __restrict__ bdec, const int* __restrict__ last_tok,
    float* __restrict__ hT) {
  __shared__ float red[4][2][64];
  int tid = threadIdx.x;
  int lane = tid & 63, wv = tid >> 6;
  int c = blockIdx.x * 64 + lane;
  int r0 = blockIdx.y * 2;
  int t0 = INIT ? BOS_ID : last_tok[r0];
  int t1 = INIT ? BOS_ID : last_tok[r0 + 1];
  const float* x0 = emb + (size_t)t0 * DMODEL + wv * 256;
  const float* x1 = emb + (size_t)t1 * DMODEL + wv * 256;
  const float* W  = Wdec + (size_t)(wv * 256) * DMODEL + c;
  float a0 = 0.f, a1 = 0.f;
  #pragma unroll 16
  for (int j = 0; j < 256; ++j) {
    float w = W[(size_t)j * DMODEL];
    a0 = fmaf(x0[j], w, a0);
    a1 = fmaf(x1[j], w, a1);
  }
  red[wv][0][lane] = a0;
  red[wv][1][lane] = a1;
  __syncthreads();
  if (wv == 0) {
    a0 = (red[0][0][lane] + red[1][0][lane]) + (red[2][0][lane] + red[3][0][lane]);
    a1 = (red[0][1][lane] + red[1][1][lane]) + (red[2][1][lane] + red[3][1][lane]);
    float bb = bdec[c];
    hT[(size_t)c * NROWS + r0]     = tanhf(a0 + bb);
    hT[(size_t)c * NROWS + r0 + 1] = tanhf(a1 + bb);
  }
}

// ---- compile-time-bounded GEMM inner loop (round-3 codegen: h scalarizes) ----
// hT/wcol must be pre-offset by the wave's (uniform) k-base.
template<int RPW, int KLEN>
__device__ __forceinline__ void gemm_ct(
    const float* __restrict__ hT, const float* __restrict__ wcol,
    int wrow0, float (&acc)[RPW]) {
  #pragma unroll 2
  for (int k0 = 0; k0 < KLEN; k0 += 16) {
    float wreg[16];
    #pragma unroll
    for (int u = 0; u < 16; ++u)
      wreg[u] = wcol[(size_t)(k0 + u) * VOCAB];
    #pragma unroll
    for (int u = 0; u < 16; ++u) {
      const float* h = hT + (size_t)(k0 + u) * NROWS + wrow0;
      if constexpr (RPW == 8) {
        float4 h0 = *(const float4*)h;
        float4 h1 = *(const float4*)(h + 4);
        acc[0] = fmaf(h0.x, wreg[u], acc[0]);
        acc[1] = fmaf(h0.y, wreg[u], acc[1]);
        acc[2] = fmaf(h0.z, wreg[u], acc[2]);
        acc[3] = fmaf(h0.w, wreg[u], acc[3]);
        acc[4] = fmaf(h1.x, wreg[u], acc[4]);
        acc[5] = fmaf(h1.y, wreg[u], acc[5]);
        acc[6] = fmaf(h1.z, wreg[u], acc[6]);
        acc[7] = fmaf(h1.w, wreg[u], acc[7]);
      } else {
        float2 h0 = *(const float2*)h;
        acc[0] = fmaf(h0.x, wreg[u], acc[0]);
        acc[1] = fmaf(h0.y, wreg[u], acc[1]);
      }
    }
  }
}

// ---- decode-step GEMM + fused partials, wave-split K ----
// grid NBLK x 1024 thr = 16 waves = 4 k-chunks (kw) x 4 row-groups (rw).
// Wave (kw,rw): rows rw*8..rw*8+7, cols blockIdx.x*64.., k in [kw*256, kw*256+256).
// kw>0 waves write acc to LDS; kw==0 waves reduce (fixed order) + epilogue.
__global__ __launch_bounds__(1024, 8) void k_logits32(
    const float* __restrict__ hT, const float* __restrict__ Wout,
    float2* __restrict__ PMS, float4* __restrict__ PV, int4* __restrict__ PI) {
  __shared__ float red[3][4][8][64];   // [kw-1][rw][r][lane] = 24 KB
  int tid = threadIdx.x;
  int lane = tid & 63, wv = tid >> 6;
  int kw = wv >> 2, rw = wv & 3;
  int c = blockIdx.x * 64 + lane;
  int p = blockIdx.x;
  int wrow0 = rw * 8;

  float acc[8];
  #pragma unroll
  for (int r = 0; r < 8; ++r) acc[r] = 0.f;

  gemm_ct<8, 256>(hT + kw * 256 * NROWS,
                  Wout + (size_t)(kw * 256) * VOCAB + c, wrow0, acc);

  if (kw > 0) {
    #pragma unroll
    for (int r = 0; r < 8; ++r) red[kw - 1][rw][r][lane] = acc[r];
  }
  __syncthreads();
  if (kw == 0) {
    #pragma unroll
    for (int r = 0; r < 8; ++r) {
      // deterministic order: kw0 + kw1 + kw2 + kw3
      acc[r] = ((acc[r] + red[0][rw][r][lane]) + red[1][rw][r][lane])
               + red[2][rw][r][lane];
    }
    #pragma unroll
    for (int r = 0; r < 8; ++r)
      row_partials(acc[r], c, wrow0 + r, p, lane, PMS, PV, PI);
  }
}

// ---- INIT-step GEMM + fused partials (8 rows, runs once) ----
__global__ __launch_bounds__(256) void k_logits_init(
    const float* __restrict__ hT, const float* __restrict__ Wout,
    float2* __restrict__ PMS, float4* __restrict__ PV, int4* __restrict__ PI) {
  int tid = threadIdx.x;
  int lane = tid & 63, wv = tid >> 6;
  int c = blockIdx.x * 64 + lane;
  int p = blockIdx.x;
  int wrow0 = wv * 2;
  float acc[2];
  acc[0] = 0.f; acc[1] = 0.f;
  gemm_ct<2, DMODEL>(hT, Wout + c, wrow0, acc);
  row_partials(acc[0], c, wrow0 + 0, p, lane, PMS, PV, PI);
  row_partials(acc[1], c, wrow0 + 1, p, lane, PMS, PV, PI);
}

// ---- kernel C: per-batch merge + state update. grid BATCH x 256 thr.
template<bool INIT>
__global__ __launch_bounds__(256) void k_batch(
    const float2* __restrict__ PMS, const float4* __restrict__ PV,
    const int4* __restrict__ PI,
    int* __restrict__ seqs, float* __restrict__ scores,
    int* __restrict__ finished, float* __restrict__ lengths,
    int* __restrict__ last_tok, int t, int wout, float* __restrict__ out) {
  __shared__ float s_lse[BEAM], s_base[BEAM];
  __shared__ int   s_fin[BEAM];
  __shared__ float s_v4[BEAM][4];
  __shared__ int   s_i4[BEAM][4];
  __shared__ float s_score[4];
  __shared__ int   s_beam[4], s_tok[4];

  int b = blockIdx.x, tid = threadIdx.x;
  int lane = tid & 63, wv = tid >> 6;
  const int R = INIT ? 1 : BEAM;

  if (wv < R) {
    int row = INIT ? b : b * BEAM + wv;
    float M = -INFINITY, S = 0.f;
    float lv[4]; int li[4];
    #pragma unroll
    for (int j = 0; j < 4; ++j) { lv[j] = -INFINITY; li[j] = INT_MAX; }
    for (int p = lane; p < NBLK; p += 64) {
      float2 ms = PMS[row * NPART + p];
      float4 pv = PV[row * NPART + p];
      int4   pi = PI[row * NPART + p];
      if (ms.x > M) { S = S * expf(M - ms.x) + ms.y; M = ms.x; }
      else          { S += ms.y * expf(ms.x - M); }
      insN<4>(pv.x, pi.x, lv, li);
      insN<4>(pv.y, pi.y, lv, li);
      insN<4>(pv.z, pi.z, lv, li);
      insN<4>(pv.w, pi.w, lv, li);
    }
    #pragma unroll
    for (int off = 32; off >= 1; off >>= 1) {
      float oM = __shfl_xor(M, off);
      float oS = __shfl_xor(S, off);
      float nM = fmaxf(M, oM);
      S = S * expf(M - nM) + oS * expf(oM - nM);
      M = nM;
    }
    int ptr = 0;
    float o4v[4]; int o4i[4];
    #pragma unroll
    for (int q = 0; q < 4; ++q) {
      float hv = -INFINITY; int hi = INT_MAX;
      #pragma unroll
      for (int j = 0; j < 4; ++j) { if (ptr == j) { hv = lv[j]; hi = li[j]; } }
      float cv = hv; int ci = hi;
      #pragma unroll
      for (int off = 32; off >= 1; off >>= 1) {
        float ov = __shfl_xor(cv, off);
        int   oi = __shfl_xor(ci, off);
        if (better(ov, oi, cv, ci)) { cv = ov; ci = oi; }
      }
      o4v[q] = cv; o4i[q] = ci;
      if (ci == hi && ci != INT_MAX) ptr++;
    }
    if (lane == 0) {
      s_lse[wv] = M + logf(S);
      #pragma unroll
      for (int q = 0; q < 4; ++q) { s_v4[wv][q] = o4v[q]; s_i4[wv][q] = o4i[q]; }
      s_base[wv] = INIT ? 0.f : scores[row];
      s_fin[wv]  = INIT ? 0 : finished[row];
    }
  }
  __syncthreads();

  if (tid == 0) {
    float fv[4]; int fi[4];
    #pragma unroll
    for (int q = 0; q < 4; ++q) { fv[q] = -INFINITY; fi[q] = INT_MAX; }
    for (int kk = 0; kk < R; ++kk) {
      if (s_fin[kk]) {
        insN<4>(s_base[kk], kk * VOCAB + PAD_ID, fv, fi);
      } else {
        float base = s_base[kk], lse = s_lse[kk];
        #pragma unroll
        for (int j = 0; j < 4; ++j)
          insN<4>(base + (s_v4[kk][j] - lse), kk * VOCAB + s_i4[kk][j], fv, fi);
      }
    }
    #pragma unroll
    for (int q = 0; q < 4; ++q) {
      s_score[q] = fv[q];
      s_beam[q]  = fi[q] / VOCAB;
      s_tok[q]   = fi[q] % VOCAB;
    }
  }
  __syncthreads();

  int k5 = tid >> 5, p5 = tid & 31;
  if (INIT) {
    if (tid < 128) {
      int val = (p5 == 0) ? BOS_ID : ((p5 == 1) ? s_tok[k5] : PAD_ID);
      seqs[(b * BEAM + k5) * MAXSEQ + p5] = val;
    }
    if (tid < 4) {
      scores[b * BEAM + tid]   = s_score[tid];
      finished[b * BEAM + tid] = (s_tok[tid] == EOS_ID) ? 1 : 0;
      lengths[b * BEAM + tid]  = 1.f;
      last_tok[b * BEAM + tid] = s_tok[tid];
    }
  } else {
    int sv = 0, oldfin = 0; float oldlen = 0.f;
    if (tid < 128) {
      sv = seqs[(b * BEAM + s_beam[k5]) * MAXSEQ + p5];
      if (p5 == t) sv = s_tok[k5];
    }
    if (tid < 4) {
      oldfin = finished[b * BEAM + s_beam[tid]];
      oldlen = lengths[b * BEAM + s_beam[tid]];
    }
    __syncthreads();
    if (tid < 128) {
      seqs[(b * BEAM + k5) * MAXSEQ + p5] = sv;
      if (wout) out[(b * BEAM + k5) * MAXSEQ + p5] = (float)sv;
    }
    if (tid < 4) {
      float nl = oldlen + (oldfin ? 0.f : 1.f);
      int   nf = (oldfin || (s_tok[tid] == EOS_ID)) ? 1 : 0;
      scores[b * BEAM + tid]   = s_score[tid];
      finished[b * BEAM + tid] = nf;
      lengths[b * BEAM + tid]  = nl;
      last_tok[b * BEAM + tid] = s_tok[tid];
      if (wout)
        out[BATCH * BEAM * MAXSEQ + b * BEAM + tid] =
            s_score[tid] / powf((5.f + nl) / 6.f, 0.6f);
    }
  }
}

extern "C" void kernel_launch(void* const* d_in, const int* in_sizes, int n_in,
                              void* d_out, int out_size, void* d_ws, size_t ws_size,
                              hipStream_t stream) {
  const float* emb  = (const float*)d_in[0];
  const float* Wdec = (const float*)d_in[1];
  const float* bdec = (const float*)d_in[2];
  const float* Wout = (const float*)d_in[3];
  float* out = (float*)d_out;

  char* ws = (char*)d_ws;
  float*  hT  = (float*) (ws + HT_OFF);
  float2* PMS = (float2*)(ws + PMS_OFF);
  float4* PV  = (float4*)(ws + PV_OFF);
  int4*   PI  = (int4*)  (ws + PI_OFF);
  int*   seqs     = (int*)  (ws + STATE_OFF);
  float* scores   = (float*)(ws + STATE_OFF + 4096);
  int*   finished = (int*)  (ws + STATE_OFF + 4224);
  float* lengths  = (float*)(ws + STATE_OFF + 4352);
  int*   last_tok = (int*)  (ws + STATE_OFF + 4480);

  // ---- initial step from <bos> (8 rows) ----
  k_embdec<true><<<dim3(DMODEL / 64, BATCH / 2), 256, 0, stream>>>(
      emb, Wdec, bdec, last_tok, hT);
  k_logits_init<<<NBLK, 256, 0, stream>>>(hT, Wout, PMS, PV, PI);
  k_batch<true><<<BATCH, 256, 0, stream>>>(PMS, PV, PI, seqs, scores, finished,
                                           lengths, last_tok, 0, 0, out);

  // ---- decode steps t = 2..31 (32 rows each) ----
  for (int t = 2; t < MAXSEQ; t++) {
    k_embdec<false><<<dim3(DMODEL / 64, NROWS / 2), 256, 0, stream>>>(
        emb, Wdec, bdec, last_tok, hT);
    k_logits32<<<NBLK, 1024, 0, stream>>>(hT, Wout, PMS, PV, PI);
    k_batch<false><<<BATCH, 256, 0, stream>>>(PMS, PV, PI, seqs, scores,
                                              finished, lengths, last_tok, t,
                                              (t == MAXSEQ - 1) ? 1 : 0, out);
  }
}

// Round 7
// 3799.309 us; speedup vs baseline: 1.5086x; 1.5086x over previous
//
#include <hip/hip_runtime.h>
#include <math.h>
#include <limits.h>

#define BATCH 8
#define BEAM 4
#define VOCAB 32000
#define DMODEL 1024
#define MAXSEQ 32
#define PAD_ID 0
#define BOS_ID 1
#define EOS_ID 2
#define NROWS 32        // BATCH*BEAM
#define NBLK 500        // VOCAB/64 partial blocks
#define NPART 512       // padded partial stride

// ---------------- workspace layout (bytes) ----------------
// hT  [DMODEL][NROWS]   f32    @ 0        (131072)
// PMS [NROWS][NPART][2] f32    @ 131072   (131072)
// PV  [NROWS][NPART][4] f32    @ 262144   (262144)
// PI  [NROWS][NPART][4] i32    @ 524288   (262144)
// state @ 786432 (seqs/scores/finished/lengths/last_tok)
#define HT_OFF     0
#define PMS_OFF    131072
#define PV_OFF     262144
#define PI_OFF     524288
#define STATE_OFF  786432

__device__ __forceinline__ bool better(float av, int ai, float bv, int bi) {
  return (av > bv) || ((av == bv) && (ai < bi));
}

// sorted-descending insert, compile-time N
template<int N>
__device__ __forceinline__ void insN(float v, int i, float tv[N], int ti[N]) {
  if (better(v, i, tv[N-1], ti[N-1])) {
    tv[N-1] = v; ti[N-1] = i;
    #pragma unroll
    for (int j = N-1; j > 0; j--) {
      if (better(tv[j], ti[j], tv[j-1], ti[j-1])) {
        float fv = tv[j]; tv[j] = tv[j-1]; tv[j-1] = fv;
        int ii = ti[j]; ti[j] = ti[j-1]; ti[j-1] = ii;
      }
    }
  }
}

// per-row epilogue: wave-wide {max, sumexp, top4} for value v at column c
__device__ __forceinline__ void row_partials(
    float v, int c, int row, int p, int lane,
    float2* __restrict__ PMS, float4* __restrict__ PV, int4* __restrict__ PI) {
  float m = v;
  #pragma unroll
  for (int off = 32; off >= 1; off >>= 1) m = fmaxf(m, __shfl_xor(m, off));
  float s = expf(v - m);
  #pragma unroll
  for (int off = 32; off >= 1; off >>= 1) s += __shfl_xor(s, off);
  float myv = v; int myc = c; bool alive = true;
  float t4v[4]; int t4i[4];
  #pragma unroll
  for (int q = 0; q < 4; ++q) {
    float cv = alive ? myv : -INFINITY;
    int   ci = alive ? myc : INT_MAX;
    #pragma unroll
    for (int off = 32; off >= 1; off >>= 1) {
      float ov = __shfl_xor(cv, off);
      int   oi = __shfl_xor(ci, off);
      if (better(ov, oi, cv, ci)) { cv = ov; ci = oi; }
    }
    t4v[q] = cv; t4i[q] = ci;
    alive = alive && (ci != myc);
  }
  if (lane == 0) {
    PMS[row * NPART + p] = make_float2(m, s);
    PV[row * NPART + p]  = make_float4(t4v[0], t4v[1], t4v[2], t4v[3]);
    PI[row * NPART + p]  = make_int4(t4i[0], t4i[1], t4i[2], t4i[3]);
  }
}

// ---- kernel A: hT[c*32+r] = tanh(emb[tok_r] . Wdec[:,c] + b[c]) ----
template<bool INIT>
__global__ __launch_bounds__(256) void k_embdec(
    const float* __restrict__ emb, const float* __restrict__ Wdec,
    const float* __restrict__ bdec, const int* __restrict__ last_tok,
    float* __restrict__ hT) {
  __shared__ float red[4][2][64];
  int tid = threadIdx.x;
  int lane = tid & 63, wv = tid >> 6;
  int c = blockIdx.x * 64 + lane;
  int r0 = blockIdx.y * 2;
  int t0 = INIT ? BOS_ID : last_tok[r0];
  int t1 = INIT ? BOS_ID : last_tok[r0 + 1];
  const float* x0 = emb + (size_t)t0 * DMODEL + wv * 256;
  const float* x1 = emb + (size_t)t1 * DMODEL + wv * 256;
  const float* W  = Wdec + (size_t)(wv * 256) * DMODEL + c;
  float a0 = 0.f, a1 = 0.f;
  #pragma unroll 16
  for (int j = 0; j < 256; ++j) {
    float w = W[(size_t)j * DMODEL];
    a0 = fmaf(x0[j], w, a0);
    a1 = fmaf(x1[j], w, a1);
  }
  red[wv][0][lane] = a0;
  red[wv][1][lane] = a1;
  __syncthreads();
  if (wv == 0) {
    a0 = (red[0][0][lane] + red[1][0][lane]) + (red[2][0][lane] + red[3][0][lane]);
    a1 = (red[0][1][lane] + red[1][1][lane]) + (red[2][1][lane] + red[3][1][lane]);
    float bb = bdec[c];
    hT[(size_t)c * NROWS + r0]     = tanhf(a0 + bb);
    hT[(size_t)c * NROWS + r0 + 1] = tanhf(a1 + bb);
  }
}

// ---- GEMM inner loop, round-3 codegen contract:
// wrow0 MUST be readfirstlane'd by the caller so h loads scalarize to
// s_load (lgkmcnt) and never enter / drain the W vmcnt prefetch chain.
// KLEN compile-time; unroll 4 => 64 W loads in flight per wave.
template<int RPW, int KLEN>
__device__ __forceinline__ void gemm_ct(
    const float* __restrict__ hT, const float* __restrict__ wcol,
    int wrow0, float (&acc)[RPW]) {
  #pragma unroll 4
  for (int k0 = 0; k0 < KLEN; k0 += 16) {
    float wreg[16];
    #pragma unroll
    for (int u = 0; u < 16; ++u)
      wreg[u] = wcol[(size_t)(k0 + u) * VOCAB];
    #pragma unroll
    for (int u = 0; u < 16; ++u) {
      const float* h = hT + (size_t)(k0 + u) * NROWS + wrow0;
      if constexpr (RPW == 8) {
        float4 h0 = *(const float4*)h;
        float4 h1 = *(const float4*)(h + 4);
        acc[0] = fmaf(h0.x, wreg[u], acc[0]);
        acc[1] = fmaf(h0.y, wreg[u], acc[1]);
        acc[2] = fmaf(h0.z, wreg[u], acc[2]);
        acc[3] = fmaf(h0.w, wreg[u], acc[3]);
        acc[4] = fmaf(h1.x, wreg[u], acc[4]);
        acc[5] = fmaf(h1.y, wreg[u], acc[5]);
        acc[6] = fmaf(h1.z, wreg[u], acc[6]);
        acc[7] = fmaf(h1.w, wreg[u], acc[7]);
      } else {
        float2 h0 = *(const float2*)h;
        acc[0] = fmaf(h0.x, wreg[u], acc[0]);
        acc[1] = fmaf(h0.y, wreg[u], acc[1]);
      }
    }
  }
}

// ---- decode-step GEMM + fused partials: 16-wave blocks, wave-split K ----
// grid NBLK x 1024 thr = 16 waves = 4 k-chunks (kw) x 4 row-groups (rw).
// Wave (kw,rw): rows rw*8..rw*8+7, k in [kw*256, kw*256+256), 64 cols.
// All waves dump acc to LDS; wave (kw,rw) then finalizes rows
// rw*8 + 2*kw + {0,1} with a fixed-order sum (deterministic).
__global__ __launch_bounds__(1024, 4) void k_logits16(
    const float* __restrict__ hT, const float* __restrict__ Wout,
    float2* __restrict__ PMS, float4* __restrict__ PV, int4* __restrict__ PI) {
  __shared__ float red[4][4][8][64];   // [kw][rw][r][lane] = 32 KB
  int tid = threadIdx.x;
  int lane = tid & 63, wv = tid >> 6;
  int kw = wv >> 2, rw = wv & 3;
  int c = blockIdx.x * 64 + lane;
  int p = blockIdx.x;
  // uniform h offset: k-chunk base * NROWS + row base (forced to SGPR)
  int wrow0 = __builtin_amdgcn_readfirstlane(kw * 256 * NROWS + rw * 8);

  float acc[8];
  #pragma unroll
  for (int r = 0; r < 8; ++r) acc[r] = 0.f;

  gemm_ct<8, 256>(hT, Wout + (size_t)(kw * 256) * VOCAB + c, wrow0, acc);

  #pragma unroll
  for (int r = 0; r < 8; ++r) red[kw][rw][r][lane] = acc[r];
  __syncthreads();

  #pragma unroll
  for (int j = 0; j < 2; ++j) {
    int r = 2 * kw + j;                 // row within this rw slab
    // deterministic order: kw0 + kw1 + kw2 + kw3
    float v = ((red[0][rw][r][lane] + red[1][rw][r][lane])
               + red[2][rw][r][lane]) + red[3][rw][r][lane];
    row_partials(v, c, rw * 8 + r, p, lane, PMS, PV, PI);
  }
}

// ---- INIT-step GEMM + fused partials (8 rows, runs once) ----
__global__ __launch_bounds__(256) void k_logits_init(
    const float* __restrict__ hT, const float* __restrict__ Wout,
    float2* __restrict__ PMS, float4* __restrict__ PV, int4* __restrict__ PI) {
  int tid = threadIdx.x;
  int lane = tid & 63, wv = tid >> 6;
  int c = blockIdx.x * 64 + lane;
  int p = blockIdx.x;
  int wrow0 = __builtin_amdgcn_readfirstlane(wv * 2);
  float acc[2];
  acc[0] = 0.f; acc[1] = 0.f;
  gemm_ct<2, DMODEL>(hT, Wout + c, wrow0, acc);
  row_partials(acc[0], c, wrow0 + 0, p, lane, PMS, PV, PI);
  row_partials(acc[1], c, wrow0 + 1, p, lane, PMS, PV, PI);
}

// ---- kernel C: per-batch merge + state update. grid BATCH x 256 thr.
template<bool INIT>
__global__ __launch_bounds__(256) void k_batch(
    const float2* __restrict__ PMS, const float4* __restrict__ PV,
    const int4* __restrict__ PI,
    int* __restrict__ seqs, float* __restrict__ scores,
    int* __restrict__ finished, float* __restrict__ lengths,
    int* __restrict__ last_tok, int t, int wout, float* __restrict__ out) {
  __shared__ float s_lse[BEAM], s_base[BEAM];
  __shared__ int   s_fin[BEAM];
  __shared__ float s_v4[BEAM][4];
  __shared__ int   s_i4[BEAM][4];
  __shared__ float s_score[4];
  __shared__ int   s_beam[4], s_tok[4];

  int b = blockIdx.x, tid = threadIdx.x;
  int lane = tid & 63, wv = tid >> 6;
  const int R = INIT ? 1 : BEAM;

  if (wv < R) {
    int row = INIT ? b : b * BEAM + wv;
    float M = -INFINITY, S = 0.f;
    float lv[4]; int li[4];
    #pragma unroll
    for (int j = 0; j < 4; ++j) { lv[j] = -INFINITY; li[j] = INT_MAX; }
    for (int p = lane; p < NBLK; p += 64) {
      float2 ms = PMS[row * NPART + p];
      float4 pv = PV[row * NPART + p];
      int4   pi = PI[row * NPART + p];
      if (ms.x > M) { S = S * expf(M - ms.x) + ms.y; M = ms.x; }
      else          { S += ms.y * expf(ms.x - M); }
      insN<4>(pv.x, pi.x, lv, li);
      insN<4>(pv.y, pi.y, lv, li);
      insN<4>(pv.z, pi.z, lv, li);
      insN<4>(pv.w, pi.w, lv, li);
    }
    #pragma unroll
    for (int off = 32; off >= 1; off >>= 1) {
      float oM = __shfl_xor(M, off);
      float oS = __shfl_xor(S, off);
      float nM = fmaxf(M, oM);
      S = S * expf(M - nM) + oS * expf(oM - nM);
      M = nM;
    }
    int ptr = 0;
    float o4v[4]; int o4i[4];
    #pragma unroll
    for (int q = 0; q < 4; ++q) {
      float hv = -INFINITY; int hi = INT_MAX;
      #pragma unroll
      for (int j = 0; j < 4; ++j) { if (ptr == j) { hv = lv[j]; hi = li[j]; } }
      float cv = hv; int ci = hi;
      #pragma unroll
      for (int off = 32; off >= 1; off >>= 1) {
        float ov = __shfl_xor(cv, off);
        int   oi = __shfl_xor(ci, off);
        if (better(ov, oi, cv, ci)) { cv = ov; ci = oi; }
      }
      o4v[q] = cv; o4i[q] = ci;
      if (ci == hi && ci != INT_MAX) ptr++;
    }
    if (lane == 0) {
      s_lse[wv] = M + logf(S);
      #pragma unroll
      for (int q = 0; q < 4; ++q) { s_v4[wv][q] = o4v[q]; s_i4[wv][q] = o4i[q]; }
      s_base[wv] = INIT ? 0.f : scores[row];
      s_fin[wv]  = INIT ? 0 : finished[row];
    }
  }
  __syncthreads();

  if (tid == 0) {
    float fv[4]; int fi[4];
    #pragma unroll
    for (int q = 0; q < 4; ++q) { fv[q] = -INFINITY; fi[q] = INT_MAX; }
    for (int kk = 0; kk < R; ++kk) {
      if (s_fin[kk]) {
        insN<4>(s_base[kk], kk * VOCAB + PAD_ID, fv, fi);
      } else {
        float base = s_base[kk], lse = s_lse[kk];
        #pragma unroll
        for (int j = 0; j < 4; ++j)
          insN<4>(base + (s_v4[kk][j] - lse), kk * VOCAB + s_i4[kk][j], fv, fi);
      }
    }
    #pragma unroll
    for (int q = 0; q < 4; ++q) {
      s_score[q] = fv[q];
      s_beam[q]  = fi[q] / VOCAB;
      s_tok[q]   = fi[q] % VOCAB;
    }
  }
  __syncthreads();

  int k5 = tid >> 5, p5 = tid & 31;
  if (INIT) {
    if (tid < 128) {
      int val = (p5 == 0) ? BOS_ID : ((p5 == 1) ? s_tok[k5] : PAD_ID);
      seqs[(b * BEAM + k5) * MAXSEQ + p5] = val;
    }
    if (tid < 4) {
      scores[b * BEAM + tid]   = s_score[tid];
      finished[b * BEAM + tid] = (s_tok[tid] == EOS_ID) ? 1 : 0;
      lengths[b * BEAM + tid]  = 1.f;
      last_tok[b * BEAM + tid] = s_tok[tid];
    }
  } else {
    int sv = 0, oldfin = 0; float oldlen = 0.f;
    if (tid < 128) {
      sv = seqs[(b * BEAM + s_beam[k5]) * MAXSEQ + p5];
      if (p5 == t) sv = s_tok[k5];
    }
    if (tid < 4) {
      oldfin = finished[b * BEAM + s_beam[tid]];
      oldlen = lengths[b * BEAM + s_beam[tid]];
    }
    __syncthreads();
    if (tid < 128) {
      seqs[(b * BEAM + k5) * MAXSEQ + p5] = sv;
      if (wout) out[(b * BEAM + k5) * MAXSEQ + p5] = (float)sv;
    }
    if (tid < 4) {
      float nl = oldlen + (oldfin ? 0.f : 1.f);
      int   nf = (oldfin || (s_tok[tid] == EOS_ID)) ? 1 : 0;
      scores[b * BEAM + tid]   = s_score[tid];
      finished[b * BEAM + tid] = nf;
      lengths[b * BEAM + tid]  = nl;
      last_tok[b * BEAM + tid] = s_tok[tid];
      if (wout)
        out[BATCH * BEAM * MAXSEQ + b * BEAM + tid] =
            s_score[tid] / powf((5.f + nl) / 6.f, 0.6f);
    }
  }
}

extern "C" void kernel_launch(void* const* d_in, const int* in_sizes, int n_in,
                              void* d_out, int out_size, void* d_ws, size_t ws_size,
                              hipStream_t stream) {
  const float* emb  = (const float*)d_in[0];
  const float* Wdec = (const float*)d_in[1];
  const float* bdec = (const float*)d_in[2];
  const float* Wout = (const float*)d_in[3];
  float* out = (float*)d_out;

  char* ws = (char*)d_ws;
  float*  hT  = (float*) (ws + HT_OFF);
  float2* PMS = (float2*)(ws + PMS_OFF);
  float4* PV  = (float4*)(ws + PV_OFF);
  int4*   PI  = (int4*)  (ws + PI_OFF);
  int*   seqs     = (int*)  (ws + STATE_OFF);
  float* scores   = (float*)(ws + STATE_OFF + 4096);
  int*   finished = (int*)  (ws + STATE_OFF + 4224);
  float* lengths  = (float*)(ws + STATE_OFF + 4352);
  int*   last_tok = (int*)  (ws + STATE_OFF + 4480);

  // ---- initial step from <bos> (8 rows) ----
  k_embdec<true><<<dim3(DMODEL / 64, BATCH / 2), 256, 0, stream>>>(
      emb, Wdec, bdec, last_tok, hT);
  k_logits_init<<<NBLK, 256, 0, stream>>>(hT, Wout, PMS, PV, PI);
  k_batch<true><<<BATCH, 256, 0, stream>>>(PMS, PV, PI, seqs, scores, finished,
                                           lengths, last_tok, 0, 0, out);

  // ---- decode steps t = 2..31 (32 rows each) ----
  for (int t = 2; t < MAXSEQ; t++) {
    k_embdec<false><<<dim3(DMODEL / 64, NROWS / 2), 256, 0, stream>>>(
        emb, Wdec, bdec, last_tok, hT);
    k_logits16<<<NBLK, 1024, 0, stream>>>(hT, Wout, PMS, PV, PI);
    k_batch<false><<<BATCH, 256, 0, stream>>>(PMS, PV, PI, seqs, scores,
                                              finished, lengths, last_tok, t,
                                              (t == MAXSEQ - 1) ? 1 : 0, out);
  }
}

// Round 8
// 3562.147 us; speedup vs baseline: 1.6091x; 1.0666x over previous
//
#include <hip/hip_runtime.h>
#include <math.h>
#include <limits.h>

#define BATCH 8
#define BEAM 4
#define VOCAB 32000
#define DMODEL 1024
#define MAXSEQ 32
#define PAD_ID 0
#define BOS_ID 1
#define EOS_ID 2
#define NROWS 32        // BATCH*BEAM
#define NBLK 500        // VOCAB/64 partial blocks
#define NPART 512       // padded partial stride

// ---------------- workspace layout (bytes) ----------------
// hT  [DMODEL][NROWS]   f32    @ 0        (131072)
// PMS [NROWS][NPART][2] f32    @ 131072   (131072)
// PV  [NROWS][NPART][4] f32    @ 262144   (262144)
// PI  [NROWS][NPART][4] i32    @ 524288   (262144)
// state @ 786432 (seqs/scores/finished/lengths/last_tok)
#define HT_OFF     0
#define PMS_OFF    131072
#define PV_OFF     262144
#define PI_OFF     524288
#define STATE_OFF  786432

__device__ __forceinline__ bool better(float av, int ai, float bv, int bi) {
  return (av > bv) || ((av == bv) && (ai < bi));
}

// sorted-descending insert, compile-time N
template<int N>
__device__ __forceinline__ void insN(float v, int i, float tv[N], int ti[N]) {
  if (better(v, i, tv[N-1], ti[N-1])) {
    tv[N-1] = v; ti[N-1] = i;
    #pragma unroll
    for (int j = N-1; j > 0; j--) {
      if (better(tv[j], ti[j], tv[j-1], ti[j-1])) {
        float fv = tv[j]; tv[j] = tv[j-1]; tv[j-1] = fv;
        int ii = ti[j]; ti[j] = ti[j-1]; ti[j-1] = ii;
      }
    }
  }
}

// per-row epilogue: wave-wide {max, sumexp, top4} for value v at column c
__device__ __forceinline__ void row_partials(
    float v, int c, int row, int p, int lane,
    float2* __restrict__ PMS, float4* __restrict__ PV, int4* __restrict__ PI) {
  float m = v;
  #pragma unroll
  for (int off = 32; off >= 1; off >>= 1) m = fmaxf(m, __shfl_xor(m, off));
  float s = expf(v - m);
  #pragma unroll
  for (int off = 32; off >= 1; off >>= 1) s += __shfl_xor(s, off);
  float myv = v; int myc = c; bool alive = true;
  float t4v[4]; int t4i[4];
  #pragma unroll
  for (int q = 0; q < 4; ++q) {
    float cv = alive ? myv : -INFINITY;
    int   ci = alive ? myc : INT_MAX;
    #pragma unroll
    for (int off = 32; off >= 1; off >>= 1) {
      float ov = __shfl_xor(cv, off);
      int   oi = __shfl_xor(ci, off);
      if (better(ov, oi, cv, ci)) { cv = ov; ci = oi; }
    }
    t4v[q] = cv; t4i[q] = ci;
    alive = alive && (ci != myc);
  }
  if (lane == 0) {
    PMS[row * NPART + p] = make_float2(m, s);
    PV[row * NPART + p]  = make_float4(t4v[0], t4v[1], t4v[2], t4v[3]);
    PI[row * NPART + p]  = make_int4(t4i[0], t4i[1], t4i[2], t4i[3]);
  }
}

// ---- kernel A: hT[c*32+r] = tanh(emb[tok_r] . Wdec[:,c] + b[c]) ----
template<bool INIT>
__global__ __launch_bounds__(256) void k_embdec(
    const float* __restrict__ emb, const float* __restrict__ Wdec,
    const float* __restrict__ bdec, const int* __restrict__ last_tok,
    float* __restrict__ hT) {
  __shared__ float red[4][2][64];
  int tid = threadIdx.x;
  int lane = tid & 63, wv = tid >> 6;
  int c = blockIdx.x * 64 + lane;
  int r0 = blockIdx.y * 2;
  int t0 = INIT ? BOS_ID : last_tok[r0];
  int t1 = INIT ? BOS_ID : last_tok[r0 + 1];
  const float* x0 = emb + (size_t)t0 * DMODEL + wv * 256;
  const float* x1 = emb + (size_t)t1 * DMODEL + wv * 256;
  const float* W  = Wdec + (size_t)(wv * 256) * DMODEL + c;
  float a0 = 0.f, a1 = 0.f;
  #pragma unroll 16
  for (int j = 0; j < 256; ++j) {
    float w = W[(size_t)j * DMODEL];
    a0 = fmaf(x0[j], w, a0);
    a1 = fmaf(x1[j], w, a1);
  }
  red[wv][0][lane] = a0;
  red[wv][1][lane] = a1;
  __syncthreads();
  if (wv == 0) {
    a0 = (red[0][0][lane] + red[1][0][lane]) + (red[2][0][lane] + red[3][0][lane]);
    a1 = (red[0][1][lane] + red[1][1][lane]) + (red[2][1][lane] + red[3][1][lane]);
    float bb = bdec[c];
    hT[(size_t)c * NROWS + r0]     = tanhf(a0 + bb);
    hT[(size_t)c * NROWS + r0 + 1] = tanhf(a1 + bb);
  }
}

// ---- kernel B: GEMM via block-cooperative LDS-staged W tiles ----
// grid NBLK x 1024 thr = 16 waves = 4 k-slices (kw) x 4 row-groups (rw).
// Per tile t (64 k x 64 cols, 16 KB): every thread stages ONE float4 of W
// (coalesced, issued BEFORE compute, written to LDS after - T14), wave
// (kw,rw) computes k-rows kw*16..+15 for rows rw*RPW..+RPW-1 from LDS
// (ds_read_b32, stride-4 linear = conflict-free); h via scalar s_load
// (readfirstlane'd uniform offset, lgkmcnt path). Double-buffered tiles.
// After the k-loop: fixed-order kw-reduce through LDS (deterministic),
// then the fused {max,sumexp,top4} epilogue.
template<int NR>
__global__ __launch_bounds__(1024, 4) void k_logits_lds(
    const float* __restrict__ hT, const float* __restrict__ Wout,
    float2* __restrict__ PMS, float4* __restrict__ PV, int4* __restrict__ PI) {
  constexpr int RPW = NR / 4;
  constexpr int NT = DMODEL / 64;       // 16 tiles of 64 k
  __shared__ __attribute__((aligned(16))) float smem[8192];  // 2x16KB; reused

  int tid = threadIdx.x;
  int lane = tid & 63, wv = tid >> 6;
  int kw = wv >> 2, rw = wv & 3;
  int c0 = blockIdx.x * 64;
  int p = blockIdx.x;

  // staging coords: thread -> (k-row sk, 4-col chunk sc) of the 64x64 tile
  int sk = tid >> 4;
  int sc = (tid & 15) << 2;
  const float* gsrc = Wout + (size_t)sk * VOCAB + c0 + sc;

  float acc[RPW];
  #pragma unroll
  for (int r = 0; r < RPW; ++r) acc[r] = 0.f;

  // prologue: stage tile 0 -> buf0
  {
    float4 st = *(const float4*)gsrc;
    *(float4*)&smem[tid * 4] = st;
  }
  __syncthreads();

  int cur = 0;
  #pragma unroll 1
  for (int t = 0; t < NT; ++t) {
    float4 stage;
    if (t + 1 < NT)
      stage = *(const float4*)(gsrc + (size_t)(t + 1) * 64 * VOCAB);  // issue early
    // compute tile t from smem[cur]
    const float* wt = &smem[cur * 4096 + kw * 16 * 64] + lane;
    int hoff = __builtin_amdgcn_readfirstlane(
        (t * 64 + kw * 16) * NROWS + rw * RPW);
    const float* hb = hT + hoff;
    #pragma unroll
    for (int u = 0; u < 16; ++u) {
      float w = wt[u * 64];                    // ds_read_b32, conflict-free
      const float* h = hb + u * NROWS;         // uniform -> s_load
      #pragma unroll
      for (int r = 0; r < RPW; ++r)
        acc[r] = fmaf(h[r], w, acc[r]);
    }
    if (t + 1 < NT)
      *(float4*)&smem[(cur ^ 1) * 4096 + tid * 4] = stage;  // write late
    __syncthreads();
    cur ^= 1;
  }

  // fixed-order kw-reduce through LDS (smem reused after barrier)
  float* red = smem;   // [kw][rw][RPW][64]
  #pragma unroll
  for (int r = 0; r < RPW; ++r)
    red[((kw * 4 + rw) * RPW + r) * 64 + lane] = acc[r];
  __syncthreads();

  for (int r = kw; r < RPW; r += 4) {
    float v = ((red[((0 * 4 + rw) * RPW + r) * 64 + lane]
              + red[((1 * 4 + rw) * RPW + r) * 64 + lane])
              + red[((2 * 4 + rw) * RPW + r) * 64 + lane])
              + red[((3 * 4 + rw) * RPW + r) * 64 + lane];
    row_partials(v, c0 + lane, rw * RPW + r, p, lane, PMS, PV, PI);
  }
}

// ---- kernel C: per-batch merge + state update. grid BATCH x 256 thr.
template<bool INIT>
__global__ __launch_bounds__(256) void k_batch(
    const float2* __restrict__ PMS, const float4* __restrict__ PV,
    const int4* __restrict__ PI,
    int* __restrict__ seqs, float* __restrict__ scores,
    int* __restrict__ finished, float* __restrict__ lengths,
    int* __restrict__ last_tok, int t, int wout, float* __restrict__ out) {
  __shared__ float s_lse[BEAM], s_base[BEAM];
  __shared__ int   s_fin[BEAM];
  __shared__ float s_v4[BEAM][4];
  __shared__ int   s_i4[BEAM][4];
  __shared__ float s_score[4];
  __shared__ int   s_beam[4], s_tok[4];

  int b = blockIdx.x, tid = threadIdx.x;
  int lane = tid & 63, wv = tid >> 6;
  const int R = INIT ? 1 : BEAM;

  if (wv < R) {
    int row = INIT ? b : b * BEAM + wv;
    float M = -INFINITY, S = 0.f;
    float lv[4]; int li[4];
    #pragma unroll
    for (int j = 0; j < 4; ++j) { lv[j] = -INFINITY; li[j] = INT_MAX; }
    for (int p = lane; p < NBLK; p += 64) {
      float2 ms = PMS[row * NPART + p];
      float4 pv = PV[row * NPART + p];
      int4   pi = PI[row * NPART + p];
      if (ms.x > M) { S = S * expf(M - ms.x) + ms.y; M = ms.x; }
      else          { S += ms.y * expf(ms.x - M); }
      insN<4>(pv.x, pi.x, lv, li);
      insN<4>(pv.y, pi.y, lv, li);
      insN<4>(pv.z, pi.z, lv, li);
      insN<4>(pv.w, pi.w, lv, li);
    }
    #pragma unroll
    for (int off = 32; off >= 1; off >>= 1) {
      float oM = __shfl_xor(M, off);
      float oS = __shfl_xor(S, off);
      float nM = fmaxf(M, oM);
      S = S * expf(M - nM) + oS * expf(oM - nM);
      M = nM;
    }
    int ptr = 0;
    float o4v[4]; int o4i[4];
    #pragma unroll
    for (int q = 0; q < 4; ++q) {
      float hv = -INFINITY; int hi = INT_MAX;
      #pragma unroll
      for (int j = 0; j < 4; ++j) { if (ptr == j) { hv = lv[j]; hi = li[j]; } }
      float cv = hv; int ci = hi;
      #pragma unroll
      for (int off = 32; off >= 1; off >>= 1) {
        float ov = __shfl_xor(cv, off);
        int   oi = __shfl_xor(ci, off);
        if (better(ov, oi, cv, ci)) { cv = ov; ci = oi; }
      }
      o4v[q] = cv; o4i[q] = ci;
      if (ci == hi && ci != INT_MAX) ptr++;
    }
    if (lane == 0) {
      s_lse[wv] = M + logf(S);
      #pragma unroll
      for (int q = 0; q < 4; ++q) { s_v4[wv][q] = o4v[q]; s_i4[wv][q] = o4i[q]; }
      s_base[wv] = INIT ? 0.f : scores[row];
      s_fin[wv]  = INIT ? 0 : finished[row];
    }
  }
  __syncthreads();

  if (tid == 0) {
    float fv[4]; int fi[4];
    #pragma unroll
    for (int q = 0; q < 4; ++q) { fv[q] = -INFINITY; fi[q] = INT_MAX; }
    for (int kk = 0; kk < R; ++kk) {
      if (s_fin[kk]) {
        insN<4>(s_base[kk], kk * VOCAB + PAD_ID, fv, fi);
      } else {
        float base = s_base[kk], lse = s_lse[kk];
        #pragma unroll
        for (int j = 0; j < 4; ++j)
          insN<4>(base + (s_v4[kk][j] - lse), kk * VOCAB + s_i4[kk][j], fv, fi);
      }
    }
    #pragma unroll
    for (int q = 0; q < 4; ++q) {
      s_score[q] = fv[q];
      s_beam[q]  = fi[q] / VOCAB;
      s_tok[q]   = fi[q] % VOCAB;
    }
  }
  __syncthreads();

  int k5 = tid >> 5, p5 = tid & 31;
  if (INIT) {
    if (tid < 128) {
      int val = (p5 == 0) ? BOS_ID : ((p5 == 1) ? s_tok[k5] : PAD_ID);
      seqs[(b * BEAM + k5) * MAXSEQ + p5] = val;
    }
    if (tid < 4) {
      scores[b * BEAM + tid]   = s_score[tid];
      finished[b * BEAM + tid] = (s_tok[tid] == EOS_ID) ? 1 : 0;
      lengths[b * BEAM + tid]  = 1.f;
      last_tok[b * BEAM + tid] = s_tok[tid];
    }
  } else {
    int sv = 0, oldfin = 0; float oldlen = 0.f;
    if (tid < 128) {
      sv = seqs[(b * BEAM + s_beam[k5]) * MAXSEQ + p5];
      if (p5 == t) sv = s_tok[k5];
    }
    if (tid < 4) {
      oldfin = finished[b * BEAM + s_beam[tid]];
      oldlen = lengths[b * BEAM + s_beam[tid]];
    }
    __syncthreads();
    if (tid < 128) {
      seqs[(b * BEAM + k5) * MAXSEQ + p5] = sv;
      if (wout) out[(b * BEAM + k5) * MAXSEQ + p5] = (float)sv;
    }
    if (tid < 4) {
      float nl = oldlen + (oldfin ? 0.f : 1.f);
      int   nf = (oldfin || (s_tok[tid] == EOS_ID)) ? 1 : 0;
      scores[b * BEAM + tid]   = s_score[tid];
      finished[b * BEAM + tid] = nf;
      lengths[b * BEAM + tid]  = nl;
      last_tok[b * BEAM + tid] = s_tok[tid];
      if (wout)
        out[BATCH * BEAM * MAXSEQ + b * BEAM + tid] =
            s_score[tid] / powf((5.f + nl) / 6.f, 0.6f);
    }
  }
}

extern "C" void kernel_launch(void* const* d_in, const int* in_sizes, int n_in,
                              void* d_out, int out_size, void* d_ws, size_t ws_size,
                              hipStream_t stream) {
  const float* emb  = (const float*)d_in[0];
  const float* Wdec = (const float*)d_in[1];
  const float* bdec = (const float*)d_in[2];
  const float* Wout = (const float*)d_in[3];
  float* out = (float*)d_out;

  char* ws = (char*)d_ws;
  float*  hT  = (float*) (ws + HT_OFF);
  float2* PMS = (float2*)(ws + PMS_OFF);
  float4* PV  = (float4*)(ws + PV_OFF);
  int4*   PI  = (int4*)  (ws + PI_OFF);
  int*   seqs     = (int*)  (ws + STATE_OFF);
  float* scores   = (float*)(ws + STATE_OFF + 4096);
  int*   finished = (int*)  (ws + STATE_OFF + 4224);
  float* lengths  = (float*)(ws + STATE_OFF + 4352);
  int*   last_tok = (int*)  (ws + STATE_OFF + 4480);

  // ---- initial step from <bos> (8 rows) ----
  k_embdec<true><<<dim3(DMODEL / 64, BATCH / 2), 256, 0, stream>>>(
      emb, Wdec, bdec, last_tok, hT);
  k_logits_lds<8><<<NBLK, 1024, 0, stream>>>(hT, Wout, PMS, PV, PI);
  k_batch<true><<<BATCH, 256, 0, stream>>>(PMS, PV, PI, seqs, scores, finished,
                                           lengths, last_tok, 0, 0, out);

  // ---- decode steps t = 2..31 (32 rows each) ----
  for (int t = 2; t < MAXSEQ; t++) {
    k_embdec<false><<<dim3(DMODEL / 64, NROWS / 2), 256, 0, stream>>>(
        emb, Wdec, bdec, last_tok, hT);
    k_logits_lds<32><<<NBLK, 1024, 0, stream>>>(hT, Wout, PMS, PV, PI);
    k_batch<false><<<BATCH, 256, 0, stream>>>(PMS, PV, PI, seqs, scores,
                                              finished, lengths, last_tok, t,
                                              (t == MAXSEQ - 1) ? 1 : 0, out);
  }
}